// Round 9
// baseline (1891.343 us; speedup 1.0000x reference)
//
#include <hip/hip_runtime.h>

#define NN 100000
#define NE 1600000
#define D  64
#define BSH 6                                  // bucket shift: 64 nodes/bucket
#define NBKT ((NN + 63) >> BSH)                // 1563
#define NBLK_E ((NE / 4 + 1023) / 1024)        // 391 blocks, 1024 int4s each
#define H_SCALE 256.0f
#define H_ISCALE 0.00390625f

typedef __attribute__((ext_vector_type(8))) short short8v;
typedef __attribute__((ext_vector_type(4))) unsigned short ushort4v;
typedef __attribute__((ext_vector_type(4))) float f32x4;
typedef __attribute__((ext_vector_type(2))) float f32x2;

__device__ __forceinline__ float bf2f(unsigned short x) {
    return __uint_as_float(((unsigned)x) << 16);
}
__device__ __forceinline__ unsigned short f2bf(float f) {  // RNE
    unsigned u = __float_as_uint(f);
    return (unsigned short)((u + 0x7fff + ((u >> 16) & 1)) >> 16);
}

// ---- zero ghist ----
__global__ void k_zero(int* __restrict__ g) {
    int i = blockIdx.x * 256 + threadIdx.x;
    if (i < NBKT) g[i] = 0;
}

// ---- pass A: global bucket histogram (LDS-staged) ----
__global__ __launch_bounds__(256) void k_hist(const int* __restrict__ row,
                                              int* __restrict__ ghist) {
    __shared__ int h[NBKT];
    int tid = threadIdx.x;
    for (int i = tid; i < NBKT; i += 256) h[i] = 0;
    __syncthreads();
    int base4 = blockIdx.x * 1024;
    #pragma unroll
    for (int k = 0; k < 4; ++k) {
        int i4 = base4 + k * 256 + tid;
        if (i4 < NE / 4) {
            int4 r = ((const int4*)row)[i4];
            atomicAdd(&h[r.x >> BSH], 1);
            atomicAdd(&h[r.y >> BSH], 1);
            atomicAdd(&h[r.z >> BSH], 1);
            atomicAdd(&h[r.w >> BSH], 1);
        }
    }
    __syncthreads();
    for (int i = tid; i < NBKT; i += 256) if (h[i]) atomicAdd(&ghist[i], h[i]);
}

// ---- pass B: exclusive scan of NBKT bucket counts (1 block, 256 thr x 8 elems) ----
__global__ __launch_bounds__(256) void k_bscan(const int* __restrict__ ghist,
                                               int* __restrict__ bbase,
                                               int* __restrict__ bcur) {
    __shared__ int s[256];
    int tid = threadIdx.x;
    int vals[8];
    int local = 0;
    #pragma unroll
    for (int k = 0; k < 8; ++k) {
        int i = tid * 8 + k;
        int v = (i < NBKT) ? ghist[i] : 0;
        vals[k] = local;              // exclusive prefix within chunk
        local += v;
    }
    s[tid] = local;
    __syncthreads();
    for (int st = 1; st < 256; st <<= 1) {
        int add = (tid >= st) ? s[tid - st] : 0;
        __syncthreads();
        s[tid] += add;
        __syncthreads();
    }
    int tbase = (tid == 0) ? 0 : s[tid - 1];
    #pragma unroll
    for (int k = 0; k < 8; ++k) {
        int i = tid * 8 + k;
        if (i <= NBKT) {
            int b = tbase + vals[k];
            bbase[i] = b;             // bbase[NBKT] == NE (trailing ghist treated as 0)
            if (i < NBKT) bcur[i] = b;
        }
    }
}

// ---- pass C: bucket-sort edges into packed u32 (lrow<<17 | col), lrow 6 bits ----
__global__ __launch_bounds__(256) void k_bucket(const int* __restrict__ row,
                                                const int* __restrict__ col,
                                                int* __restrict__ bcur,
                                                unsigned* __restrict__ sorted) {
    __shared__ int hist[NBKT];
    __shared__ int bbase_s[NBKT];
    int tid = threadIdx.x;
    for (int i = tid; i < NBKT; i += 256) hist[i] = 0;
    __syncthreads();
    int base4 = blockIdx.x * 1024;
    int4 r4[4], c4[4];
    int rank[16];
    bool valid[4];
    #pragma unroll
    for (int k = 0; k < 4; ++k) {
        int i4 = base4 + k * 256 + tid;
        valid[k] = (i4 < NE / 4);
        if (valid[k]) {
            r4[k] = ((const int4*)row)[i4];
            c4[k] = ((const int4*)col)[i4];
            rank[k * 4 + 0] = atomicAdd(&hist[r4[k].x >> BSH], 1);
            rank[k * 4 + 1] = atomicAdd(&hist[r4[k].y >> BSH], 1);
            rank[k * 4 + 2] = atomicAdd(&hist[r4[k].z >> BSH], 1);
            rank[k * 4 + 3] = atomicAdd(&hist[r4[k].w >> BSH], 1);
        }
    }
    __syncthreads();
    for (int i = tid; i < NBKT; i += 256)
        bbase_s[i] = hist[i] ? atomicAdd(&bcur[i], hist[i]) : 0;
    __syncthreads();
    #pragma unroll
    for (int k = 0; k < 4; ++k) {
        if (valid[k]) {
            int rr[4] = {r4[k].x, r4[k].y, r4[k].z, r4[k].w};
            int cc[4] = {c4[k].x, c4[k].y, c4[k].z, c4[k].w};
            #pragma unroll
            for (int j = 0; j < 4; ++j) {
                int b = rr[j] >> BSH;
                unsigned pk = ((unsigned)(rr[j] & 63) << 17) | (unsigned)cc[j];
                sorted[bbase_s[b] + rank[k * 4 + j]] = pk;
            }
        }
    }
}

// ---- per-node degree from sorted buckets (replaces k_fine) ----
__global__ __launch_bounds__(256) void k_cnt(const unsigned* __restrict__ sorted,
                                             const int* __restrict__ bbase,
                                             int* __restrict__ cnt) {
    __shared__ int h[64];
    int b = blockIdx.x, tid = threadIdx.x;
    if (tid < 64) h[tid] = 0;
    __syncthreads();
    int s0 = bbase[b], e0 = bbase[b + 1];
    for (int i = s0 + tid; i < e0; i += 256) atomicAdd(&h[sorted[i] >> 17], 1);
    __syncthreads();
    int gnode = b * 64 + tid;
    if (tid < 64 && gnode < NN) cnt[gnode] = h[tid];
}

// ---- c[o] = sum_k W3[o][k] * relu(W4[k]) ----
__global__ void k_cvec(const float* __restrict__ W3, const float* __restrict__ W4,
                       float* __restrict__ c) {
    int o = threadIdx.x;  // 64 threads
    float s = 0.f;
    for (int k = 0; k < D; ++k) {
        float w4 = W4[k];
        s += W3[o * D + k] * (w4 > 0.f ? w4 : 0.f);
    }
    c[o] = s;
}

// ---- W1, W2 fp32 -> bf16 ----
__global__ void k_wprep(const float* __restrict__ W1, const float* __restrict__ W2,
                        unsigned short* __restrict__ w1b, unsigned short* __restrict__ w2b) {
    int i = blockIdx.x * 256 + threadIdx.x;
    if (i < D * D) {
        w1b[i] = f2bf(W1[i]);
        w2b[i] = f2bf(W2[i]);
    }
}

// ---- base_bf = bf16(Xv@W1.T + deg*c) via MFMA; emb_bf = bf16(relu(.)) ----
__global__ __launch_bounds__(256) void k_base(
        const float* __restrict__ Xv, const unsigned short* __restrict__ w1b,
        const int* __restrict__ cnt, const float* __restrict__ cvec,
        unsigned short* __restrict__ base_bf, unsigned short* __restrict__ emb_bf) {
    int wid = blockIdx.x * 4 + (threadIdx.x >> 6);
    int lane = threadIdx.x & 63;
    int m0 = wid * 16;
    if (m0 >= NN) return;
    int r = lane & 15, half = lane >> 4;
    const float* arow = Xv + (size_t)(m0 + r) * D + half * 8;
    f32x4 xa = *(const f32x4*)(arow);
    f32x4 xb = *(const f32x4*)(arow + 4);
    f32x4 xc = *(const f32x4*)(arow + 32);
    f32x4 xd = *(const f32x4*)(arow + 36);
    short8v a0, a1;
    #pragma unroll
    for (int j = 0; j < 4; ++j) {
        a0[j]     = (short)f2bf(xa[j]);
        a0[j + 4] = (short)f2bf(xb[j]);
        a1[j]     = (short)f2bf(xc[j]);
        a1[j + 4] = (short)f2bf(xd[j]);
    }
    int4 c4 = *(const int4*)(cnt + m0 + half * 4);    // deg of the 4 C-rows this lane holds
    float dg[4] = {(float)c4.x, (float)c4.y, (float)c4.z, (float)c4.w};
    #pragma unroll
    for (int t = 0; t < 4; ++t) {
        short8v b0 = *(const short8v*)(w1b + (size_t)(t * 16 + r) * D + half * 8);
        short8v b1 = *(const short8v*)(w1b + (size_t)(t * 16 + r) * D + 32 + half * 8);
        f32x4 cacc = {0.f, 0.f, 0.f, 0.f};
        cacc = __builtin_amdgcn_mfma_f32_16x16x32_bf16(a0, b0, cacc, 0, 0, 0);
        cacc = __builtin_amdgcn_mfma_f32_16x16x32_bf16(a1, b1, cacc, 0, 0, 0);
        float cv = cvec[t * 16 + r];
        #pragma unroll
        for (int q = 0; q < 4; ++q) {
            float s = cacc[q] + dg[q] * cv;
            size_t idx = (size_t)(m0 + half * 4 + q) * D + t * 16 + r;
            base_bf[idx] = f2bf(s);
            emb_bf[idx] = f2bf(s > 0.f ? s : 0.f);
        }
    }
}

// ---- h8 = fp8_e4m3( (emb_bf @ W2bf.T) * H_SCALE ) via MFMA, 16 nodes/wave ----
__global__ __launch_bounds__(256) void k_h(
        const unsigned short* __restrict__ emb_bf, const unsigned short* __restrict__ w2b,
        unsigned char* __restrict__ h8) {
    int wid = blockIdx.x * 4 + (threadIdx.x >> 6);
    int lane = threadIdx.x & 63;
    int m0 = wid * 16;
    if (m0 >= NN) return;
    int r = lane & 15, half = lane >> 4;
    const unsigned short* arow = emb_bf + (size_t)(m0 + r) * D + half * 8;
    short8v a0 = *(const short8v*)(arow);
    short8v a1 = *(const short8v*)(arow + 32);
    #pragma unroll
    for (int t = 0; t < 4; ++t) {
        short8v b0 = *(const short8v*)(w2b + (size_t)(t * 16 + r) * D + half * 8);
        short8v b1 = *(const short8v*)(w2b + (size_t)(t * 16 + r) * D + 32 + half * 8);
        f32x4 cacc = {0.f, 0.f, 0.f, 0.f};
        cacc = __builtin_amdgcn_mfma_f32_16x16x32_bf16(a0, b0, cacc, 0, 0, 0);
        cacc = __builtin_amdgcn_mfma_f32_16x16x32_bf16(a1, b1, cacc, 0, 0, 0);
        #pragma unroll
        for (int q = 0; q < 4; ++q) {
            int pk = __builtin_amdgcn_cvt_pk_fp8_f32(cacc[q] * H_SCALE, 0.f, 0, false);
            h8[(size_t)(m0 + half * 4 + q) * D + t * 16 + r] = (unsigned char)(pk & 0xff);
        }
    }
}

// ---- edge-centric pull: one block per 64-node bucket, LDS fp32 accumulation ----
// emb[i] = relu(base[i] + (1/S) * sum_{j in N(i)} h8[col_j]); edges read
// coalesced from sorted[], gather is the only random access (2 in flight/wave).
template<int LAST>
__global__ __launch_bounds__(256) void k_pull(
        const unsigned* __restrict__ sorted, const int* __restrict__ bbase,
        const unsigned char* __restrict__ h8,
        const unsigned short* __restrict__ base_bf,
        unsigned short* __restrict__ out_bf, float* __restrict__ out_f32) {
    __shared__ float acc[64][66];   // +2 pad: atomic bank = (2*lrow + 8*l + u) & 31
    int tid = threadIdx.x;
    int b = blockIdx.x;
    for (int i = tid; i < 64 * 66; i += 256) ((float*)acc)[i] = 0.f;
    int s0 = bbase[b], e0 = bbase[b + 1];
    int wave = tid >> 6, lane = tid & 63, g = lane >> 3, l = lane & 7;
    __syncthreads();
    // wave w owns 8-edge chunks at ib = s0 + w*8 + 64k and ib+32 (2 gathers in flight)
    for (int ib = s0 + wave * 8; ib < e0; ib += 64) {
        int ea = ib + g;
        int eb = ib + 32 + g;
        bool da = (ea < e0), db = (eb < e0);
        unsigned pka = da ? sorted[ea] : 0u;
        unsigned pkb = db ? sorted[eb] : 0u;
        uint2 va, vb;
        if (da) va = *((const uint2*)(h8 + (size_t)(pka & 0x1FFFFu) * D) + l);
        if (db) vb = *((const uint2*)(h8 + (size_t)(pkb & 0x1FFFFu) * D) + l);
        if (da) {
            f32x2 f0 = __builtin_amdgcn_cvt_pk_f32_fp8(va.x, false);
            f32x2 f1 = __builtin_amdgcn_cvt_pk_f32_fp8(va.x, true);
            f32x2 f2 = __builtin_amdgcn_cvt_pk_f32_fp8(va.y, false);
            f32x2 f3 = __builtin_amdgcn_cvt_pk_f32_fp8(va.y, true);
            float* a = &acc[pka >> 17][l * 8];
            atomicAdd(a + 0, f0.x); atomicAdd(a + 1, f0.y);
            atomicAdd(a + 2, f1.x); atomicAdd(a + 3, f1.y);
            atomicAdd(a + 4, f2.x); atomicAdd(a + 5, f2.y);
            atomicAdd(a + 6, f3.x); atomicAdd(a + 7, f3.y);
        }
        if (db) {
            f32x2 f0 = __builtin_amdgcn_cvt_pk_f32_fp8(vb.x, false);
            f32x2 f1 = __builtin_amdgcn_cvt_pk_f32_fp8(vb.x, true);
            f32x2 f2 = __builtin_amdgcn_cvt_pk_f32_fp8(vb.y, false);
            f32x2 f3 = __builtin_amdgcn_cvt_pk_f32_fp8(vb.y, true);
            float* a = &acc[pkb >> 17][l * 8];
            atomicAdd(a + 0, f0.x); atomicAdd(a + 1, f0.y);
            atomicAdd(a + 2, f1.x); atomicAdd(a + 3, f1.y);
            atomicAdd(a + 4, f2.x); atomicAdd(a + 5, f2.y);
            atomicAdd(a + 6, f3.x); atomicAdd(a + 7, f3.y);
        }
    }
    __syncthreads();
    // epilogue: 64 nodes x 64 ch = 2048 float2s, 8 per thread, coalesced
    #pragma unroll
    for (int k = 0; k < 8; ++k) {
        int f2i = k * 256 + tid;
        int elem = f2i * 2;
        int node = elem >> 6, ch = elem & 63;
        int gnode = b * 64 + node;
        if (gnode < NN) {
            f32x2 av = *(const f32x2*)&acc[node][ch];   // 8B-aligned (66*4 % 8 == 0)
            unsigned bp = *(const unsigned*)(base_bf + (size_t)gnode * D + ch);
            float b0 = bf2f((unsigned short)(bp & 0xffff));
            float b1 = bf2f((unsigned short)(bp >> 16));
            float r0 = fmaxf(fmaf(av.x, H_ISCALE, b0), 0.f);
            float r1 = fmaxf(fmaf(av.y, H_ISCALE, b1), 0.f);
            if (LAST) {
                f32x2 o2 = {r0, r1};
                *(f32x2*)(out_f32 + (size_t)gnode * D + ch) = o2;
            } else {
                unsigned op = (unsigned)f2bf(r0) | ((unsigned)f2bf(r1) << 16);
                *(unsigned*)(out_bf + (size_t)gnode * D + ch) = op;
            }
        }
    }
}

extern "C" void kernel_launch(void* const* d_in, const int* in_sizes, int n_in,
                              void* d_out, int out_size, void* d_ws, size_t ws_size,
                              hipStream_t stream) {
    const float* Xv = (const float*)d_in[0];
    const int*   ei = (const int*)d_in[1];
    const float* W1 = (const float*)d_in[2];
    const float* W2 = (const float*)d_in[3];
    const float* W3 = (const float*)d_in[4];
    const float* W4 = (const float*)d_in[5];

    char* ws = (char*)d_ws;
    size_t off = 0;
    unsigned short* base_bf = (unsigned short*)(ws + off); off += (size_t)NN * D * 2; // 12.8 MB
    unsigned char* h8 = (unsigned char*)(ws + off);    off += (size_t)NN * D;      // 6.4 MB
    int* cnt     = (int*)(ws + off);                   off += (size_t)NN * 4;
    int* ghist   = (int*)(ws + off);                   off += NBKT * 4;
    int* bbase   = (int*)(ws + off);                   off += (NBKT + 1) * 4;
    int* bcur    = (int*)(ws + off);                   off += NBKT * 4;
    float* cvec  = (float*)(ws + off);                 off += D * 4;
    unsigned short* w1b = (unsigned short*)(ws + off); off += D * D * 2;
    unsigned short* w2b = (unsigned short*)(ws + off); off += D * D * 2;
    off = (off + 15) & ~(size_t)15;
    unsigned* sorted = (unsigned*)(ws + off);          off += (size_t)NE * 4;      // 6.4 MB

    // intermediate bf16 emb lives in d_out's bytes (final step overwrites with fp32)
    unsigned short* emb_bf = (unsigned short*)d_out;
    float* emb_f32 = (float*)d_out;

    const int* row = ei;
    const int* col = ei + NE;

    // ---- edge bucketing: two-level multisplit into sorted[] (dense writes) ----
    k_zero<<<(NBKT + 255) / 256, 256, 0, stream>>>(ghist);
    k_hist<<<NBLK_E, 256, 0, stream>>>(row, ghist);
    k_bscan<<<1, 256, 0, stream>>>(ghist, bbase, bcur);
    k_bucket<<<NBLK_E, 256, 0, stream>>>(row, col, bcur, sorted);
    k_cnt<<<NBKT, 256, 0, stream>>>(sorted, bbase, cnt);

    // ---- weights prep + base, emb1 = relu(base) ----
    k_cvec<<<1, 64, 0, stream>>>(W3, W4, cvec);
    k_wprep<<<16, 256, 0, stream>>>(W1, W2, w1b, w2b);
    k_base<<<(NN / 16 + 3) / 4, 256, 0, stream>>>(Xv, w1b, cnt, cvec, base_bf, emb_bf);

    // ---- 3 remaining message-passing steps ----
    for (int t = 0; t < 3; ++t) {
        k_h<<<(NN / 16 + 3) / 4, 256, 0, stream>>>(emb_bf, w2b, h8);
        if (t < 2)
            k_pull<0><<<NBKT, 256, 0, stream>>>(sorted, bbase, h8, base_bf, emb_bf, nullptr);
        else
            k_pull<1><<<NBKT, 256, 0, stream>>>(sorted, bbase, h8, base_bf, nullptr, emb_f32);
    }
}

// Round 10
// 316.192 us; speedup vs baseline: 5.9816x; 5.9816x over previous
//
#include <hip/hip_runtime.h>

#define NN 100000
#define NE 1600000
#define D  64
#define BSH 8                                  // bucket shift: 256 nodes/bucket
#define NBKT ((NN + 255) >> BSH)               // 391
#define NBLK_E ((NE / 4 + 1023) / 1024)        // 391 blocks, 1024 int4s each
#define H_SCALE 256.0f
#define H_ISCALE 0.00390625f

typedef __attribute__((ext_vector_type(8))) short short8v;
typedef __attribute__((ext_vector_type(4))) unsigned short ushort4v;
typedef __attribute__((ext_vector_type(4))) float f32x4;
typedef __attribute__((ext_vector_type(2))) float f32x2;

__device__ __forceinline__ float bf2f(unsigned short x) {
    return __uint_as_float(((unsigned)x) << 16);
}
__device__ __forceinline__ unsigned short f2bf(float f) {  // RNE
    unsigned u = __float_as_uint(f);
    return (unsigned short)((u + 0x7fff + ((u >> 16) & 1)) >> 16);
}

// ---- zero ghist ----
__global__ void k_zero(int* __restrict__ g) {
    int i = blockIdx.x * 256 + threadIdx.x;
    if (i < NBKT) g[i] = 0;
}

// ---- pass A: global bucket histogram (LDS-staged) ----
__global__ __launch_bounds__(256) void k_hist(const int* __restrict__ row,
                                              int* __restrict__ ghist) {
    __shared__ int h[NBKT];
    int tid = threadIdx.x;
    for (int i = tid; i < NBKT; i += 256) h[i] = 0;
    __syncthreads();
    int base4 = blockIdx.x * 1024;
    #pragma unroll
    for (int k = 0; k < 4; ++k) {
        int i4 = base4 + k * 256 + tid;
        if (i4 < NE / 4) {
            int4 r = ((const int4*)row)[i4];
            atomicAdd(&h[r.x >> BSH], 1);
            atomicAdd(&h[r.y >> BSH], 1);
            atomicAdd(&h[r.z >> BSH], 1);
            atomicAdd(&h[r.w >> BSH], 1);
        }
    }
    __syncthreads();
    for (int i = tid; i < NBKT; i += 256) if (h[i]) atomicAdd(&ghist[i], h[i]);
}

// ---- pass B: exclusive scan of 391 bucket counts (1 block) ----
__global__ __launch_bounds__(256) void k_bscan(const int* __restrict__ ghist,
                                               int* __restrict__ bbase,
                                               int* __restrict__ bcur) {
    __shared__ int sc[2][512];
    int t = threadIdx.x;
    int cur = 0;
    #pragma unroll
    for (int k = 0; k < 2; ++k) {
        int i = t + k * 256;
        sc[0][i] = (i < NBKT) ? ghist[i] : 0;
    }
    __syncthreads();
    for (int s = 1; s < 512; s <<= 1) {
        #pragma unroll
        for (int k = 0; k < 2; ++k) {
            int i = t + k * 256;
            sc[cur ^ 1][i] = sc[cur][i] + ((i >= s) ? sc[cur][i - s] : 0);
        }
        cur ^= 1;
        __syncthreads();
    }
    #pragma unroll
    for (int k = 0; k < 2; ++k) {
        int i = t + k * 256;
        if (i < NBKT) {
            int b = (i == 0) ? 0 : sc[cur][i - 1];
            bbase[i] = b;
            bcur[i] = b;
        } else if (i == NBKT) {
            bbase[NBKT] = sc[cur][NBKT - 1];   // = NE
        }
    }
}

// ---- pass C: bucket-sort edges into packed u32 (lrow<<17 | col) ----
__global__ __launch_bounds__(256) void k_bucket(const int* __restrict__ row,
                                                const int* __restrict__ col,
                                                int* __restrict__ bcur,
                                                unsigned* __restrict__ sorted) {
    __shared__ int hist[NBKT];
    __shared__ int bbase_s[NBKT];
    int tid = threadIdx.x;
    for (int i = tid; i < NBKT; i += 256) hist[i] = 0;
    __syncthreads();
    int base4 = blockIdx.x * 1024;
    int4 r4[4], c4[4];
    int rank[16];
    bool valid[4];
    #pragma unroll
    for (int k = 0; k < 4; ++k) {
        int i4 = base4 + k * 256 + tid;
        valid[k] = (i4 < NE / 4);
        if (valid[k]) {
            r4[k] = ((const int4*)row)[i4];
            c4[k] = ((const int4*)col)[i4];
            rank[k * 4 + 0] = atomicAdd(&hist[r4[k].x >> BSH], 1);
            rank[k * 4 + 1] = atomicAdd(&hist[r4[k].y >> BSH], 1);
            rank[k * 4 + 2] = atomicAdd(&hist[r4[k].z >> BSH], 1);
            rank[k * 4 + 3] = atomicAdd(&hist[r4[k].w >> BSH], 1);
        }
    }
    __syncthreads();
    for (int i = tid; i < NBKT; i += 256)
        bbase_s[i] = hist[i] ? atomicAdd(&bcur[i], hist[i]) : 0;
    __syncthreads();
    #pragma unroll
    for (int k = 0; k < 4; ++k) {
        if (valid[k]) {
            int rr[4] = {r4[k].x, r4[k].y, r4[k].z, r4[k].w};
            int cc[4] = {c4[k].x, c4[k].y, c4[k].z, c4[k].w};
            #pragma unroll
            for (int j = 0; j < 4; ++j) {
                int b = rr[j] >> BSH;
                unsigned pk = ((unsigned)(rr[j] & 255) << 17) | (unsigned)cc[j];
                sorted[bbase_s[b] + rank[k * 4 + j]] = pk;
            }
        }
    }
}

// ---- pass D: per-bucket fine CSR (LDS count -> scan -> scatter) ----
__global__ __launch_bounds__(256) void k_fine(const unsigned* __restrict__ sorted,
                                              const int* __restrict__ bbase,
                                              int* __restrict__ csr_col,
                                              int* __restrict__ cnt_g,
                                              int2* __restrict__ se_g) {
    __shared__ int cnt_s[256];
    __shared__ int cur_s[256];
    __shared__ int sc[2][256];
    int b = blockIdx.x;
    int tid = threadIdx.x;
    int s0 = bbase[b], e0 = bbase[b + 1];
    cnt_s[tid] = 0;
    __syncthreads();
    for (int i = s0 + tid; i < e0; i += 256)
        atomicAdd(&cnt_s[sorted[i] >> 17], 1);
    __syncthreads();
    int cur = 0;
    sc[0][tid] = cnt_s[tid];
    __syncthreads();
    for (int s = 1; s < 256; s <<= 1) {
        sc[cur ^ 1][tid] = sc[cur][tid] + ((tid >= s) ? sc[cur][tid - s] : 0);
        cur ^= 1;
        __syncthreads();
    }
    int incl = sc[cur][tid];
    cur_s[tid] = incl - cnt_s[tid];           // exclusive offset
    int nb = NN - b * 256;
    nb = nb > 256 ? 256 : nb;
    if (tid < nb) {
        int node = b * 256 + tid;
        cnt_g[node] = cnt_s[tid];
        se_g[node] = make_int2(s0 + incl - cnt_s[tid], s0 + incl);
    }
    __syncthreads();
    for (int i = s0 + tid; i < e0; i += 256) {
        unsigned u = sorted[i];
        int p = atomicAdd(&cur_s[u >> 17], 1);
        csr_col[s0 + p] = (int)(u & 0x1FFFFu);
    }
}

// ---- c[o] = sum_k W3[o][k] * relu(W4[k]) ----
__global__ void k_cvec(const float* __restrict__ W3, const float* __restrict__ W4,
                       float* __restrict__ c) {
    int o = threadIdx.x;  // 64 threads
    float s = 0.f;
    for (int k = 0; k < D; ++k) {
        float w4 = W4[k];
        s += W3[o * D + k] * (w4 > 0.f ? w4 : 0.f);
    }
    c[o] = s;
}

// ---- W1, W2 fp32 -> bf16 ----
__global__ void k_wprep(const float* __restrict__ W1, const float* __restrict__ W2,
                        unsigned short* __restrict__ w1b, unsigned short* __restrict__ w2b) {
    int i = blockIdx.x * 256 + threadIdx.x;
    if (i < D * D) {
        w1b[i] = f2bf(W1[i]);
        w2b[i] = f2bf(W2[i]);
    }
}

// ---- base_bf = bf16(Xv@W1.T + deg*c) via MFMA; emb_bf = bf16(relu(.)) ----
__global__ __launch_bounds__(256) void k_base(
        const float* __restrict__ Xv, const unsigned short* __restrict__ w1b,
        const int* __restrict__ cnt, const float* __restrict__ cvec,
        unsigned short* __restrict__ base_bf, unsigned short* __restrict__ emb_bf) {
    int wid = blockIdx.x * 4 + (threadIdx.x >> 6);
    int lane = threadIdx.x & 63;
    int m0 = wid * 16;
    if (m0 >= NN) return;
    int r = lane & 15, half = lane >> 4;
    const float* arow = Xv + (size_t)(m0 + r) * D + half * 8;
    f32x4 xa = *(const f32x4*)(arow);
    f32x4 xb = *(const f32x4*)(arow + 4);
    f32x4 xc = *(const f32x4*)(arow + 32);
    f32x4 xd = *(const f32x4*)(arow + 36);
    short8v a0, a1;
    #pragma unroll
    for (int j = 0; j < 4; ++j) {
        a0[j]     = (short)f2bf(xa[j]);
        a0[j + 4] = (short)f2bf(xb[j]);
        a1[j]     = (short)f2bf(xc[j]);
        a1[j + 4] = (short)f2bf(xd[j]);
    }
    int4 c4 = *(const int4*)(cnt + m0 + half * 4);    // deg of the 4 C-rows this lane holds
    float dg[4] = {(float)c4.x, (float)c4.y, (float)c4.z, (float)c4.w};
    #pragma unroll
    for (int t = 0; t < 4; ++t) {
        short8v b0 = *(const short8v*)(w1b + (size_t)(t * 16 + r) * D + half * 8);
        short8v b1 = *(const short8v*)(w1b + (size_t)(t * 16 + r) * D + 32 + half * 8);
        f32x4 cacc = {0.f, 0.f, 0.f, 0.f};
        cacc = __builtin_amdgcn_mfma_f32_16x16x32_bf16(a0, b0, cacc, 0, 0, 0);
        cacc = __builtin_amdgcn_mfma_f32_16x16x32_bf16(a1, b1, cacc, 0, 0, 0);
        float cv = cvec[t * 16 + r];
        #pragma unroll
        for (int q = 0; q < 4; ++q) {
            float s = cacc[q] + dg[q] * cv;
            size_t idx = (size_t)(m0 + half * 4 + q) * D + t * 16 + r;
            base_bf[idx] = f2bf(s);
            emb_bf[idx] = f2bf(s > 0.f ? s : 0.f);
        }
    }
}

// ---- h8 = fp8_e4m3( (emb_bf @ W2bf.T) * H_SCALE ) via MFMA, 16 nodes/wave ----
__global__ __launch_bounds__(256) void k_h(
        const unsigned short* __restrict__ emb_bf, const unsigned short* __restrict__ w2b,
        unsigned char* __restrict__ h8) {
    int wid = blockIdx.x * 4 + (threadIdx.x >> 6);
    int lane = threadIdx.x & 63;
    int m0 = wid * 16;
    if (m0 >= NN) return;
    int r = lane & 15, half = lane >> 4;
    const unsigned short* arow = emb_bf + (size_t)(m0 + r) * D + half * 8;
    short8v a0 = *(const short8v*)(arow);
    short8v a1 = *(const short8v*)(arow + 32);
    #pragma unroll
    for (int t = 0; t < 4; ++t) {
        short8v b0 = *(const short8v*)(w2b + (size_t)(t * 16 + r) * D + half * 8);
        short8v b1 = *(const short8v*)(w2b + (size_t)(t * 16 + r) * D + 32 + half * 8);
        f32x4 cacc = {0.f, 0.f, 0.f, 0.f};
        cacc = __builtin_amdgcn_mfma_f32_16x16x32_bf16(a0, b0, cacc, 0, 0, 0);
        cacc = __builtin_amdgcn_mfma_f32_16x16x32_bf16(a1, b1, cacc, 0, 0, 0);
        #pragma unroll
        for (int q = 0; q < 4; ++q) {
            int pk = __builtin_amdgcn_cvt_pk_fp8_f32(cacc[q] * H_SCALE, 0.f, 0, false);
            h8[(size_t)(m0 + half * 4 + q) * D + t * 16 + r] = (unsigned char)(pk & 0xff);
        }
    }
}

// ---- decode+accumulate 8 fp8 from a uint2 ----
__device__ __forceinline__ void acc8(float* acc, const uint2& v) {
    f32x2 f;
    f = __builtin_amdgcn_cvt_pk_f32_fp8(v.x, false); acc[0] += f.x; acc[1] += f.y;
    f = __builtin_amdgcn_cvt_pk_f32_fp8(v.x, true);  acc[2] += f.x; acc[3] += f.y;
    f = __builtin_amdgcn_cvt_pk_f32_fp8(v.y, false); acc[4] += f.x; acc[5] += f.y;
    f = __builtin_amdgcn_cvt_pk_f32_fp8(v.y, true);  acc[6] += f.x; acc[7] += f.y;
}

// ---- emb[i] = relu(base[i] + (1/S) * sum_{j in N(i)} h8[csr_col[j]]) ----
// Round-6 per-node algorithm, but each wave interleaves TWO nodes' edge loops:
// 4 independent index->gather chains in flight (was 2) to cover L2/L3 latency.
template<int LAST>
__global__ __launch_bounds__(256) void k_pull(
        const int2* __restrict__ se_g,
        const int* __restrict__ csr_col, const unsigned char* __restrict__ h8,
        const unsigned short* __restrict__ base_bf,
        unsigned short* __restrict__ out_bf, float* __restrict__ out_f32) {
    int tid = threadIdx.x;
    int wave = tid >> 6, lane = tid & 63;
    int g = lane >> 3, l = lane & 7;   // group g: edges e == g (mod 8); lane: ch l*8..+7
    for (int it = blockIdx.x; it < NN / 8; it += gridDim.x) {
        int nodeA = it * 8 + wave * 2;
        int nodeB = nodeA + 1;
        int2 seA = se_g[nodeA];
        int2 seB = se_g[nodeB];
        float accA[8] = {0.f, 0.f, 0.f, 0.f, 0.f, 0.f, 0.f, 0.f};
        float accB[8] = {0.f, 0.f, 0.f, 0.f, 0.f, 0.f, 0.f, 0.f};
        int ja = seA.x + g, ea = seA.y;
        int jb = seB.x + g, eb = seB.y;
        while (ja < ea || jb < eb) {
            int cA0 = (ja < ea)     ? csr_col[ja]     : -1;
            int cA1 = (ja + 8 < ea) ? csr_col[ja + 8] : -1;
            int cB0 = (jb < eb)     ? csr_col[jb]     : -1;
            int cB1 = (jb + 8 < eb) ? csr_col[jb + 8] : -1;
            uint2 vA0, vA1, vB0, vB1;
            if (cA0 >= 0) vA0 = *((const uint2*)(h8 + (size_t)cA0 * D) + l);
            if (cA1 >= 0) vA1 = *((const uint2*)(h8 + (size_t)cA1 * D) + l);
            if (cB0 >= 0) vB0 = *((const uint2*)(h8 + (size_t)cB0 * D) + l);
            if (cB1 >= 0) vB1 = *((const uint2*)(h8 + (size_t)cB1 * D) + l);
            if (cA0 >= 0) acc8(accA, vA0);
            if (cA1 >= 0) acc8(accA, vA1);
            if (cB0 >= 0) acc8(accB, vB0);
            if (cB1 >= 0) acc8(accB, vB1);
            ja += 16; jb += 16;
        }
        // butterfly over the 8 groups (lane bits 3,4,5) for both nodes
        #pragma unroll
        for (int m = 8; m < 64; m <<= 1) {
            #pragma unroll
            for (int u = 0; u < 8; ++u) {
                accA[u] += __shfl_xor(accA[u], m);
                accB[u] += __shfl_xor(accB[u], m);
            }
        }
        // epilogue: g in {0,1} stores node A, g in {4,5} stores node B (disjoint lanes)
        if (g < 2 || (g >= 4 && g < 6)) {
            int isB = (g >= 4);
            int gg = g & 3;                  // 0 or 1
            int node = isB ? nodeB : nodeA;
            const float* ac = isB ? accB : accA;
            int off = l * 8 + gg * 4;
            ushort4v b4 = *(const ushort4v*)(base_bf + (size_t)node * D + off);
            float rr[4];
            #pragma unroll
            for (int u = 0; u < 4; ++u) {
                float a = gg ? ac[u + 4] : ac[u];
                rr[u] = fmaxf(fmaf(a, H_ISCALE, bf2f(b4[u])), 0.f);
            }
            if (LAST) {
                f32x4 o4 = {rr[0], rr[1], rr[2], rr[3]};
                *(f32x4*)(out_f32 + (size_t)node * D + off) = o4;
            } else {
                ushort4v o4;
                #pragma unroll
                for (int u = 0; u < 4; ++u) o4[u] = f2bf(rr[u]);
                *(ushort4v*)(out_bf + (size_t)node * D + off) = o4;
            }
        }
    }
}

extern "C" void kernel_launch(void* const* d_in, const int* in_sizes, int n_in,
                              void* d_out, int out_size, void* d_ws, size_t ws_size,
                              hipStream_t stream) {
    const float* Xv = (const float*)d_in[0];
    const int*   ei = (const int*)d_in[1];
    const float* W1 = (const float*)d_in[2];
    const float* W2 = (const float*)d_in[3];
    const float* W3 = (const float*)d_in[4];
    const float* W4 = (const float*)d_in[5];

    char* ws = (char*)d_ws;
    size_t off = 0;
    unsigned short* base_bf = (unsigned short*)(ws + off); off += (size_t)NN * D * 2; // 12.8 MB
    unsigned char* h8 = (unsigned char*)(ws + off);    off += (size_t)NN * D;      // 6.4 MB
    int* csr_col = (int*)(ws + off);                   off += (size_t)NE * 4;      // 6.4 MB
    int* cnt     = (int*)(ws + off);                   off += (size_t)NN * 4;
    int2* se_g   = (int2*)(ws + off);                  off += (size_t)NN * 8;
    int* ghist   = (int*)(ws + off);                   off += NBKT * 4;
    int* bbase   = (int*)(ws + off);                   off += (NBKT + 1) * 4;
    int* bcur    = (int*)(ws + off);                   off += NBKT * 4;
    float* cvec  = (float*)(ws + off);                 off += D * 4;
    unsigned short* w1b = (unsigned short*)(ws + off); off += D * D * 2;
    unsigned short* w2b = (unsigned short*)(ws + off); off += D * D * 2;
    unsigned* sorted = (unsigned*)(ws + off);          off += (size_t)NE * 4;      // 6.4 MB

    // intermediate bf16 emb lives in d_out's bytes (final step overwrites with fp32)
    unsigned short* emb_bf = (unsigned short*)d_out;
    float* emb_f32 = (float*)d_out;

    const int* row = ei;
    const int* col = ei + NE;

    // ---- CSR build: two-level multisplit (dense writes) ----
    k_zero<<<2, 256, 0, stream>>>(ghist);
    k_hist<<<NBLK_E, 256, 0, stream>>>(row, ghist);
    k_bscan<<<1, 256, 0, stream>>>(ghist, bbase, bcur);
    k_bucket<<<NBLK_E, 256, 0, stream>>>(row, col, bcur, sorted);
    k_fine<<<NBKT, 256, 0, stream>>>(sorted, bbase, csr_col, cnt, se_g);

    // ---- weights prep + base, emb1 = relu(base) ----
    k_cvec<<<1, 64, 0, stream>>>(W3, W4, cvec);
    k_wprep<<<16, 256, 0, stream>>>(W1, W2, w1b, w2b);
    k_base<<<(NN / 16 + 3) / 4, 256, 0, stream>>>(Xv, w1b, cnt, cvec, base_bf, emb_bf);

    // ---- 3 remaining message-passing steps ----
    for (int t = 0; t < 3; ++t) {
        k_h<<<(NN / 16 + 3) / 4, 256, 0, stream>>>(emb_bf, w2b, h8);
        if (t < 2)
            k_pull<0><<<2048, 256, 0, stream>>>(se_g, csr_col, h8, base_bf, emb_bf, nullptr);
        else
            k_pull<1><<<2048, 256, 0, stream>>>(se_g, csr_col, h8, base_bf, nullptr, emb_f32);
    }
}

// Round 11
// 231.512 us; speedup vs baseline: 8.1695x; 1.3658x over previous
//
#include <hip/hip_runtime.h>

#define NN 100000
#define NE 1600000
#define D  64
#define BSH 8                                  // bucket shift: 256 nodes/bucket
#define NBKT ((NN + 255) >> BSH)               // 391
#define NBLK_E ((NE / 4 + 1023) / 1024)        // 391 blocks, 1024 int4s each
#define H_SCALE 256.0f
#define H_ISCALE 0.00390625f

typedef __attribute__((ext_vector_type(8))) short short8v;
typedef __attribute__((ext_vector_type(4))) unsigned short ushort4v;
typedef __attribute__((ext_vector_type(4))) float f32x4;
typedef __attribute__((ext_vector_type(2))) float f32x2;

__device__ __forceinline__ float bf2f(unsigned short x) {
    return __uint_as_float(((unsigned)x) << 16);
}
__device__ __forceinline__ unsigned short f2bf(float f) {  // RNE
    unsigned u = __float_as_uint(f);
    return (unsigned short)((u + 0x7fff + ((u >> 16) & 1)) >> 16);
}

// ---- fused prep: W1/W2 -> bf16, cvec, zero ghist (replaces 3 tiny kernels) ----
__global__ __launch_bounds__(256) void k_prep(
        const float* __restrict__ W1, const float* __restrict__ W2,
        const float* __restrict__ W3, const float* __restrict__ W4,
        unsigned short* __restrict__ w1b, unsigned short* __restrict__ w2b,
        float* __restrict__ cvec, int* __restrict__ ghist) {
    int b = blockIdx.x, tid = threadIdx.x;
    if (b < 16) {
        int i = b * 256 + tid;
        w1b[i] = f2bf(W1[i]);
        w2b[i] = f2bf(W2[i]);
    } else {
        for (int i = tid; i < NBKT; i += 256) ghist[i] = 0;
        if (tid < 64) {
            float s = 0.f;
            for (int k = 0; k < D; ++k) {
                float w4 = W4[k];
                s += W3[tid * D + k] * (w4 > 0.f ? w4 : 0.f);
            }
            cvec[tid] = s;
        }
    }
}

// ---- pass A: global bucket histogram (LDS-staged) ----
__global__ __launch_bounds__(256) void k_hist(const int* __restrict__ row,
                                              int* __restrict__ ghist) {
    __shared__ int h[NBKT];
    int tid = threadIdx.x;
    for (int i = tid; i < NBKT; i += 256) h[i] = 0;
    __syncthreads();
    int base4 = blockIdx.x * 1024;
    #pragma unroll
    for (int k = 0; k < 4; ++k) {
        int i4 = base4 + k * 256 + tid;
        if (i4 < NE / 4) {
            int4 r = ((const int4*)row)[i4];
            atomicAdd(&h[r.x >> BSH], 1);
            atomicAdd(&h[r.y >> BSH], 1);
            atomicAdd(&h[r.z >> BSH], 1);
            atomicAdd(&h[r.w >> BSH], 1);
        }
    }
    __syncthreads();
    for (int i = tid; i < NBKT; i += 256) if (h[i]) atomicAdd(&ghist[i], h[i]);
}

// ---- pass B: exclusive scan of 391 bucket counts (1 block) ----
__global__ __launch_bounds__(256) void k_bscan(const int* __restrict__ ghist,
                                               int* __restrict__ bbase,
                                               int* __restrict__ bcur) {
    __shared__ int sc[2][512];
    int t = threadIdx.x;
    int cur = 0;
    #pragma unroll
    for (int k = 0; k < 2; ++k) {
        int i = t + k * 256;
        sc[0][i] = (i < NBKT) ? ghist[i] : 0;
    }
    __syncthreads();
    for (int s = 1; s < 512; s <<= 1) {
        #pragma unroll
        for (int k = 0; k < 2; ++k) {
            int i = t + k * 256;
            sc[cur ^ 1][i] = sc[cur][i] + ((i >= s) ? sc[cur][i - s] : 0);
        }
        cur ^= 1;
        __syncthreads();
    }
    #pragma unroll
    for (int k = 0; k < 2; ++k) {
        int i = t + k * 256;
        if (i < NBKT) {
            int b = (i == 0) ? 0 : sc[cur][i - 1];
            bbase[i] = b;
            bcur[i] = b;
        } else if (i == NBKT) {
            bbase[NBKT] = sc[cur][NBKT - 1];   // = NE
        }
    }
}

// ---- pass C: bucket-sort edges into packed u32 (lrow<<17 | col) ----
__global__ __launch_bounds__(256) void k_bucket(const int* __restrict__ row,
                                                const int* __restrict__ col,
                                                int* __restrict__ bcur,
                                                unsigned* __restrict__ sorted) {
    __shared__ int hist[NBKT];
    __shared__ int bbase_s[NBKT];
    int tid = threadIdx.x;
    for (int i = tid; i < NBKT; i += 256) hist[i] = 0;
    __syncthreads();
    int base4 = blockIdx.x * 1024;
    int4 r4[4], c4[4];
    int rank[16];
    bool valid[4];
    #pragma unroll
    for (int k = 0; k < 4; ++k) {
        int i4 = base4 + k * 256 + tid;
        valid[k] = (i4 < NE / 4);
        if (valid[k]) {
            r4[k] = ((const int4*)row)[i4];
            c4[k] = ((const int4*)col)[i4];
            rank[k * 4 + 0] = atomicAdd(&hist[r4[k].x >> BSH], 1);
            rank[k * 4 + 1] = atomicAdd(&hist[r4[k].y >> BSH], 1);
            rank[k * 4 + 2] = atomicAdd(&hist[r4[k].z >> BSH], 1);
            rank[k * 4 + 3] = atomicAdd(&hist[r4[k].w >> BSH], 1);
        }
    }
    __syncthreads();
    for (int i = tid; i < NBKT; i += 256)
        bbase_s[i] = hist[i] ? atomicAdd(&bcur[i], hist[i]) : 0;
    __syncthreads();
    #pragma unroll
    for (int k = 0; k < 4; ++k) {
        if (valid[k]) {
            int rr[4] = {r4[k].x, r4[k].y, r4[k].z, r4[k].w};
            int cc[4] = {c4[k].x, c4[k].y, c4[k].z, c4[k].w};
            #pragma unroll
            for (int j = 0; j < 4; ++j) {
                int b = rr[j] >> BSH;
                unsigned pk = ((unsigned)(rr[j] & 255) << 17) | (unsigned)cc[j];
                sorted[bbase_s[b] + rank[k * 4 + j]] = pk;
            }
        }
    }
}

// ---- pass D: per-bucket fine CSR (LDS count -> scan -> scatter) ----
__global__ __launch_bounds__(256) void k_fine(const unsigned* __restrict__ sorted,
                                              const int* __restrict__ bbase,
                                              int* __restrict__ csr_col,
                                              int* __restrict__ cnt_g,
                                              int2* __restrict__ se_g) {
    __shared__ int cnt_s[256];
    __shared__ int cur_s[256];
    __shared__ int sc[2][256];
    int b = blockIdx.x;
    int tid = threadIdx.x;
    int s0 = bbase[b], e0 = bbase[b + 1];
    cnt_s[tid] = 0;
    __syncthreads();
    for (int i = s0 + tid; i < e0; i += 256)
        atomicAdd(&cnt_s[sorted[i] >> 17], 1);
    __syncthreads();
    int cur = 0;
    sc[0][tid] = cnt_s[tid];
    __syncthreads();
    for (int s = 1; s < 256; s <<= 1) {
        sc[cur ^ 1][tid] = sc[cur][tid] + ((tid >= s) ? sc[cur][tid - s] : 0);
        cur ^= 1;
        __syncthreads();
    }
    int incl = sc[cur][tid];
    cur_s[tid] = incl - cnt_s[tid];           // exclusive offset
    int nb = NN - b * 256;
    nb = nb > 256 ? 256 : nb;
    if (tid < nb) {
        int node = b * 256 + tid;
        cnt_g[node] = cnt_s[tid];
        se_g[node] = make_int2(s0 + incl - cnt_s[tid], s0 + incl);
    }
    __syncthreads();
    for (int i = s0 + tid; i < e0; i += 256) {
        unsigned u = sorted[i];
        int p = atomicAdd(&cur_s[u >> 17], 1);
        csr_col[s0 + p] = (int)(u & 0x1FFFFu);
    }
}

// ---- base_bf = bf16(Xv@W1.T + deg*c) via MFMA; emb_bf = bf16(relu(.)) ----
__global__ __launch_bounds__(256) void k_base(
        const float* __restrict__ Xv, const unsigned short* __restrict__ w1b,
        const int* __restrict__ cnt, const float* __restrict__ cvec,
        unsigned short* __restrict__ base_bf, unsigned short* __restrict__ emb_bf) {
    int wid = blockIdx.x * 4 + (threadIdx.x >> 6);
    int lane = threadIdx.x & 63;
    int m0 = wid * 16;
    if (m0 >= NN) return;
    int r = lane & 15, half = lane >> 4;
    const float* arow = Xv + (size_t)(m0 + r) * D + half * 8;
    f32x4 xa = *(const f32x4*)(arow);
    f32x4 xb = *(const f32x4*)(arow + 4);
    f32x4 xc = *(const f32x4*)(arow + 32);
    f32x4 xd = *(const f32x4*)(arow + 36);
    short8v a0, a1;
    #pragma unroll
    for (int j = 0; j < 4; ++j) {
        a0[j]     = (short)f2bf(xa[j]);
        a0[j + 4] = (short)f2bf(xb[j]);
        a1[j]     = (short)f2bf(xc[j]);
        a1[j + 4] = (short)f2bf(xd[j]);
    }
    int4 c4 = *(const int4*)(cnt + m0 + half * 4);    // deg of the 4 C-rows this lane holds
    float dg[4] = {(float)c4.x, (float)c4.y, (float)c4.z, (float)c4.w};
    #pragma unroll
    for (int t = 0; t < 4; ++t) {
        short8v b0 = *(const short8v*)(w1b + (size_t)(t * 16 + r) * D + half * 8);
        short8v b1 = *(const short8v*)(w1b + (size_t)(t * 16 + r) * D + 32 + half * 8);
        f32x4 cacc = {0.f, 0.f, 0.f, 0.f};
        cacc = __builtin_amdgcn_mfma_f32_16x16x32_bf16(a0, b0, cacc, 0, 0, 0);
        cacc = __builtin_amdgcn_mfma_f32_16x16x32_bf16(a1, b1, cacc, 0, 0, 0);
        float cv = cvec[t * 16 + r];
        #pragma unroll
        for (int q = 0; q < 4; ++q) {
            float s = cacc[q] + dg[q] * cv;
            size_t idx = (size_t)(m0 + half * 4 + q) * D + t * 16 + r;
            base_bf[idx] = f2bf(s);
            emb_bf[idx] = f2bf(s > 0.f ? s : 0.f);
        }
    }
}

// ---- h8 = fp8_e4m3( (emb_bf @ W2bf.T) * H_SCALE ) via MFMA, 16 nodes/wave ----
__global__ __launch_bounds__(256) void k_h(
        const unsigned short* __restrict__ emb_bf, const unsigned short* __restrict__ w2b,
        unsigned char* __restrict__ h8) {
    int wid = blockIdx.x * 4 + (threadIdx.x >> 6);
    int lane = threadIdx.x & 63;
    int m0 = wid * 16;
    if (m0 >= NN) return;
    int r = lane & 15, half = lane >> 4;
    const unsigned short* arow = emb_bf + (size_t)(m0 + r) * D + half * 8;
    short8v a0 = *(const short8v*)(arow);
    short8v a1 = *(const short8v*)(arow + 32);
    #pragma unroll
    for (int t = 0; t < 4; ++t) {
        short8v b0 = *(const short8v*)(w2b + (size_t)(t * 16 + r) * D + half * 8);
        short8v b1 = *(const short8v*)(w2b + (size_t)(t * 16 + r) * D + 32 + half * 8);
        f32x4 cacc = {0.f, 0.f, 0.f, 0.f};
        cacc = __builtin_amdgcn_mfma_f32_16x16x32_bf16(a0, b0, cacc, 0, 0, 0);
        cacc = __builtin_amdgcn_mfma_f32_16x16x32_bf16(a1, b1, cacc, 0, 0, 0);
        #pragma unroll
        for (int q = 0; q < 4; ++q) {
            int pk = __builtin_amdgcn_cvt_pk_fp8_f32(cacc[q] * H_SCALE, 0.f, 0, false);
            h8[(size_t)(m0 + half * 4 + q) * D + t * 16 + r] = (unsigned char)(pk & 0xff);
        }
    }
}

// ---- emb[i] = relu(base[i] + (1/S) * sum_{j in N(i)} h8[csr_col[j]]) ----
// Channel-transposed pull: 16 lanes per edge, lane owns 4 CHANNELS (uint = 4 fp8).
// Accumulation is in-lane; only 2 shfl_xor folds (x16, x32) per node instead of
// the round-6 butterfly's 120 ds_bpermute -> removes the DS-pipe bottleneck.
template<int LAST>
__global__ __launch_bounds__(256) void k_pull(
        const int2* __restrict__ se_g,
        const int* __restrict__ csr_col, const unsigned char* __restrict__ h8,
        const unsigned short* __restrict__ base_bf,
        unsigned short* __restrict__ out_bf, float* __restrict__ out_f32) {
    int tid = threadIdx.x;
    int wave = tid >> 6, lane = tid & 63;
    int q = lane >> 4, l = lane & 15;   // edge slot q (0..3), channel group l: ch 4l..4l+3
    for (int it = blockIdx.x; it < NN / 4; it += gridDim.x) {
        int node = it * 4 + wave;
        int2 se = se_g[node];
        int start = se.x, end = se.y;
        float a0 = 0.f, a1 = 0.f, a2 = 0.f, a3 = 0.f;
        for (int j = start; j < end; j += 8) {      // 8 edges per trip (2 slots x 4 q)
            int e0 = j + q;
            int e1 = j + 4 + q;
            int c0 = (e0 < end) ? csr_col[e0] : -1;   // 16 lanes same addr: TCC broadcast
            int c1 = (e1 < end) ? csr_col[e1] : -1;
            unsigned v0 = 0, v1 = 0;
            if (c0 >= 0) v0 = *((const unsigned*)(h8 + (size_t)c0 * D) + l);  // 64B/edge
            if (c1 >= 0) v1 = *((const unsigned*)(h8 + (size_t)c1 * D) + l);
            if (c0 >= 0) {
                f32x2 f0 = __builtin_amdgcn_cvt_pk_f32_fp8(v0, false);
                f32x2 f1 = __builtin_amdgcn_cvt_pk_f32_fp8(v0, true);
                a0 += f0.x; a1 += f0.y; a2 += f1.x; a3 += f1.y;
            }
            if (c1 >= 0) {
                f32x2 f0 = __builtin_amdgcn_cvt_pk_f32_fp8(v1, false);
                f32x2 f1 = __builtin_amdgcn_cvt_pk_f32_fp8(v1, true);
                a0 += f0.x; a1 += f0.y; a2 += f1.x; a3 += f1.y;
            }
        }
        // fold the 4 edge slots: lanes with same l, q in {0..3} -> 8 DS ops total
        a0 += __shfl_xor(a0, 16); a1 += __shfl_xor(a1, 16);
        a2 += __shfl_xor(a2, 16); a3 += __shfl_xor(a3, 16);
        a0 += __shfl_xor(a0, 32); a1 += __shfl_xor(a1, 32);
        a2 += __shfl_xor(a2, 32); a3 += __shfl_xor(a3, 32);
        if (q == 0) {   // 16 lanes: lane l covers ch 4l..4l+3 (256B contiguous store)
            ushort4v b4 = *(const ushort4v*)(base_bf + (size_t)node * D + l * 4);
            float r0 = fmaxf(fmaf(a0, H_ISCALE, bf2f(b4[0])), 0.f);
            float r1 = fmaxf(fmaf(a1, H_ISCALE, bf2f(b4[1])), 0.f);
            float r2 = fmaxf(fmaf(a2, H_ISCALE, bf2f(b4[2])), 0.f);
            float r3 = fmaxf(fmaf(a3, H_ISCALE, bf2f(b4[3])), 0.f);
            if (LAST) {
                f32x4 o4 = {r0, r1, r2, r3};
                *(f32x4*)(out_f32 + (size_t)node * D + l * 4) = o4;
            } else {
                ushort4v o4 = {f2bf(r0), f2bf(r1), f2bf(r2), f2bf(r3)};
                *(ushort4v*)(out_bf + (size_t)node * D + l * 4) = o4;
            }
        }
    }
}

extern "C" void kernel_launch(void* const* d_in, const int* in_sizes, int n_in,
                              void* d_out, int out_size, void* d_ws, size_t ws_size,
                              hipStream_t stream) {
    const float* Xv = (const float*)d_in[0];
    const int*   ei = (const int*)d_in[1];
    const float* W1 = (const float*)d_in[2];
    const float* W2 = (const float*)d_in[3];
    const float* W3 = (const float*)d_in[4];
    const float* W4 = (const float*)d_in[5];

    char* ws = (char*)d_ws;
    size_t off = 0;
    unsigned short* base_bf = (unsigned short*)(ws + off); off += (size_t)NN * D * 2; // 12.8 MB
    unsigned char* h8 = (unsigned char*)(ws + off);    off += (size_t)NN * D;      // 6.4 MB
    int* csr_col = (int*)(ws + off);                   off += (size_t)NE * 4;      // 6.4 MB
    int* cnt     = (int*)(ws + off);                   off += (size_t)NN * 4;
    int2* se_g   = (int2*)(ws + off);                  off += (size_t)NN * 8;
    int* ghist   = (int*)(ws + off);                   off += NBKT * 4;
    int* bbase   = (int*)(ws + off);                   off += (NBKT + 1) * 4;
    int* bcur    = (int*)(ws + off);                   off += NBKT * 4;
    float* cvec  = (float*)(ws + off);                 off += D * 4;
    unsigned short* w1b = (unsigned short*)(ws + off); off += D * D * 2;
    unsigned short* w2b = (unsigned short*)(ws + off); off += D * D * 2;
    unsigned* sorted = (unsigned*)(ws + off);          off += (size_t)NE * 4;      // 6.4 MB

    // intermediate bf16 emb lives in d_out's bytes (final step overwrites with fp32)
    unsigned short* emb_bf = (unsigned short*)d_out;
    float* emb_f32 = (float*)d_out;

    const int* row = ei;
    const int* col = ei + NE;

    // ---- prep (fused) + CSR build: two-level multisplit (dense writes) ----
    k_prep<<<17, 256, 0, stream>>>(W1, W2, W3, W4, w1b, w2b, cvec, ghist);
    k_hist<<<NBLK_E, 256, 0, stream>>>(row, ghist);
    k_bscan<<<1, 256, 0, stream>>>(ghist, bbase, bcur);
    k_bucket<<<NBLK_E, 256, 0, stream>>>(row, col, bcur, sorted);
    k_fine<<<NBKT, 256, 0, stream>>>(sorted, bbase, csr_col, cnt, se_g);

    // ---- base, emb1 = relu(base) ----
    k_base<<<(NN / 16 + 3) / 4, 256, 0, stream>>>(Xv, w1b, cnt, cvec, base_bf, emb_bf);

    // ---- 3 remaining message-passing steps ----
    for (int t = 0; t < 3; ++t) {
        k_h<<<(NN / 16 + 3) / 4, 256, 0, stream>>>(emb_bf, w2b, h8);
        if (t < 2)
            k_pull<0><<<2048, 256, 0, stream>>>(se_g, csr_col, h8, base_bf, emb_bf, nullptr);
        else
            k_pull<1><<<2048, 256, 0, stream>>>(se_g, csr_col, h8, base_bf, nullptr, emb_f32);
    }
}